// Round 11
// baseline (529.646 us; speedup 1.0000x reference)
//
#include <hip/hip_runtime.h>
#include <cstdint>

using u16 = unsigned short;
using u32 = unsigned int;
using f32x4  = __attribute__((ext_vector_type(4))) float;
using bf16x8 = __attribute__((ext_vector_type(8))) short;

#define NHEADS 3
#define WSZ 8
#define IMG 256
#define NPX 65536          // pixels per image
#define NWIN 33            // windows per side
#define ATT_SCALE 0.17677669529663687f
#define INV_SCALE 5.656854249492381f
#define SM_C 0.25505102572168217f    // ATT_SCALE * log2(e)
#define HALO_PITCH 104     // u16 per halo pixel (208 B: 96 ch + 8 pad -> conflict-free)

__device__ __forceinline__ int refl(int i, int n) {
    return i < 0 ? -i : (i >= n ? 2*n - 2 - i : i);
}
__device__ __forceinline__ float bflo(u32 u){ union{u32 i; float f;} x; x.i = u << 16; return x.f; }
__device__ __forceinline__ float bfhi(u32 u){ union{u32 i; float f;} x; x.i = u & 0xffff0000u; return x.f; }
__device__ __forceinline__ float bf2f(u16 v){ union{u32 i; float f;} x; x.i = ((u32)v) << 16; return x.f; }
__device__ __forceinline__ u16 f2bf(float f){
    union{float f; u32 i;} x; x.f = f;
    u32 r = x.i + 0x7fffu + ((x.i >> 16) & 1u);
    return (u16)(r >> 16);
}
__device__ __forceinline__ u32 pk2bf(float a, float b){
    return (u32)f2bf(a) | ((u32)f2bf(b) << 16);
}

// ---------------------------------------------------------------- bias table
// biasS[h][q][key] = bias[h][q][key] / ATT_SCALE   (scale folded into exp arg)
__global__ __launch_bounds__(256) void k_bias(
    const float* __restrict__ m1w, const float* __restrict__ m1b,
    const float* __restrict__ m2w, const float* __restrict__ m2b,
    float* __restrict__ biasS)
{
    int idx = blockIdx.x * 256 + threadIdx.x;   // 0..12287
    int hh  = idx >> 12;
    int rem = idx & 4095;
    int n = rem >> 6, m = rem & 63;             // n = query, m = key
    int di = (n >> 3) - (m >> 3);
    int dj = (n & 7)  - (m & 7);
    float fdi = copysignf(log1pf(fabsf((float)di)), (float)di);
    float fdj = copysignf(log1pf(fabsf((float)dj)), (float)dj);
    float acc = m2b[hh];
    for (int k = 0; k < 256; ++k) {
        float tv = fdi * m1w[2*k] + fdj * m1w[2*k+1] + m1b[k];
        float g  = 0.5f * tv * (1.0f + erff(tv * 0.70710678118654752f));
        acc = fmaf(g, m2w[hh*256 + k], acc);
    }
    biasS[hh*4096 + n*64 + m] = acc * INV_SCALE;
}

// ---------------------------------------------------------------- conv weight pre-pack
__global__ __launch_bounds__(64) void k_wprep(
    const float* __restrict__ cw, u16* __restrict__ Bfrag)
{
    int ks   = blockIdx.x;        // 0..161 = (ck*9+tap)*6+nt
    int lane = threadIdx.x;
    int nt    = ks % 6;
    int kstep = ks / 6;
    int tap   = kstep % 9;
    int ck    = kstep / 9;
    int dy = tap / 3, dx = tap % 3;
    int cout = nt*16 + (lane & 15);
    int cin0 = ck*32 + (lane >> 4)*8;
    u16* dst = Bfrag + (size_t)ks*512 + lane*8;
    #pragma unroll
    for (int j = 0; j < 8; ++j)
        dst[j] = f2bf(cw[((size_t)(cout*96 + cin0 + j))*9 + dy*3 + dx]);
}

// ---------------------------------------------------------------- QKV weight pre-pack
__global__ __launch_bounds__(64) void k_wprep_qkv(
    const float* __restrict__ qkw, const float* __restrict__ vw,
    u16* __restrict__ BfragQ)
{
    int ks   = blockIdx.x;        // 0..53 = kstep*18 + nt
    int lane = threadIdx.x;
    int nt    = ks % 18;
    int kstep = ks / 18;
    int o     = nt*16 + (lane & 15);
    int cin0  = kstep*32 + (lane >> 4)*8;
    const float* src = (o < 192) ? (qkw + (size_t)o*96 + cin0)
                                 : (vw + (size_t)(o - 192)*96 + cin0);
    u16* dst = BfragQ + (size_t)ks*512 + lane*8;
    #pragma unroll
    for (int j = 0; j < 8; ++j) dst[j] = f2bf(src[j]);
}

// ---------------------------------------------------------------- proj weight pre-pack
__global__ __launch_bounds__(64) void k_wprep_proj(
    const float* __restrict__ pw, u16* __restrict__ BfragP)
{
    int ks   = blockIdx.x;        // 0..17 = kstep*6 + nt
    int lane = threadIdx.x;
    int nt    = ks % 6;
    int kstep = ks / 6;
    int o     = nt*16 + (lane & 15);
    int cin0  = kstep*32 + (lane >> 4)*8;
    u16* dst = BfragP + (size_t)ks*512 + lane*8;
    #pragma unroll
    for (int j = 0; j < 8; ++j) dst[j] = f2bf(pw[(size_t)o*96 + cin0 + j]);
}

// ---------------------------------------------------------------- QKV 1x1 conv (MFMA, fused x-transpose)
__global__ __launch_bounds__(256, 2) void k_qkv(
    const float* __restrict__ x, const u16* __restrict__ BfragQ,
    const float* __restrict__ qkb, const float* __restrict__ vb,
    u16* __restrict__ qkv)
{
    int tile = blockIdx.x;                 // 0..2047
    int b    = tile >> 8;
    int pix0 = (tile & 255) * 256;
    size_t px0 = (size_t)tile * 256;       // = b*NPX + pix0
    int t    = threadIdx.x;

    __shared__ u16 xs[256 * HALO_PITCH];   // 53,248 B

    {
        const float* xb = x + (size_t)b*96*NPX + pix0 + t;
        u16* xrow = xs + t * HALO_PITCH;
        float v[96];
        #pragma unroll
        for (int c = 0; c < 96; ++c) v[c] = xb[(size_t)c * NPX];
        #pragma unroll
        for (int oct = 0; oct < 12; ++oct) {
            uint4 o;
            o.x = pk2bf(v[oct*8+0], v[oct*8+1]);
            o.y = pk2bf(v[oct*8+2], v[oct*8+3]);
            o.z = pk2bf(v[oct*8+4], v[oct*8+5]);
            o.w = pk2bf(v[oct*8+6], v[oct*8+7]);
            *(uint4*)(xrow + oct*8) = o;
        }
    }
    __syncthreads();

    int wv   = __builtin_amdgcn_readfirstlane(t >> 6);
    int lane = t & 63;
    int lc   = lane & 15;
    int kg   = lane >> 4;

    const u16* bbase = BfragQ + lane*8;

    #pragma unroll 1
    for (int og = 0; og < 3; ++og) {
        f32x4 acc[4][6] = {};
        #pragma unroll
        for (int kstep = 0; kstep < 3; ++kstep) {
            bf16x8 bF[6];
            #pragma unroll
            for (int nt = 0; nt < 6; ++nt)
                bF[nt] = *(const bf16x8*)(bbase + (size_t)(kstep*18 + og*6 + nt)*512);
            #pragma unroll
            for (int mt = 0; mt < 4; ++mt) {
                bf16x8 aF = *(const bf16x8*)(xs + (wv*64 + mt*16 + lc)*HALO_PITCH + kstep*32 + kg*8);
                #pragma unroll
                for (int nt = 0; nt < 6; ++nt)
                    acc[mt][nt] = __builtin_amdgcn_mfma_f32_16x16x32_bf16(aF, bF[nt], acc[mt][nt], 0, 0, 0);
            }
        }

        float bv[6];
        #pragma unroll
        for (int nt = 0; nt < 6; ++nt) {
            int o = og*96 + nt*16 + lc;
            bv[nt] = (o < 192) ? qkb[o] : vb[o - 192];
        }

        #pragma unroll
        for (int mt = 0; mt < 4; ++mt) {
            #pragma unroll
            for (int r = 0; r < 4; ++r) {
                size_t px = px0 + wv*64 + mt*16 + kg*4 + r;
                u16* qp = qkv + px*288 + og*96 + lc;
                #pragma unroll
                for (int nt = 0; nt < 6; ++nt)
                    qp[nt*16] = f2bf(acc[mt][nt][r] + bv[nt]);
            }
        }
    }
}

// ---------------------------------------------------------------- window attention (MFMA 16x16, hoisted-QK pipeline)
// 1 wave per window, 4 waves/block. Swapped QK^T: D[key][q] = mfma(K, Q, bias/scale).
// Per head: ALL 4 q-blocks' QK^T computed upfront (acc[4][4]), then a per-block
// stream softmax -> P[16][72] LDS (reused, same-wave DS order makes WAR safe)
// -> PV -> store. The 4 softmax chains are independent -> cross-block ILP hides
// the serial max/exp/LDS-roundtrip latency that bounded R9.
// LDS unchanged: 27,648 B/block.
__global__ __launch_bounds__(256, 4) void k_attn(
    const u16* __restrict__ qkv, const float* __restrict__ biasS,
    u16* __restrict__ att)
{
    __shared__ u16 lds[4 * 3456];        // 4 waves x (P[16][72] + Vt[32][72])
    int t    = threadIdx.x;
    int wv   = __builtin_amdgcn_readfirstlane(t >> 6);
    int lane = t & 63;
    int lc   = lane & 15;
    int kg   = lane >> 4;

    u16* Plds = lds + wv * 3456;         // [16][72] bf16
    u16* Vlds = Plds + 1152;             // [32][72] bf16

    int win = blockIdx.x * 4 + wv;       // 0..8711
    int b   = win / 1089;
    int wr  = win - b * 1089;
    int wy  = wr / NWIN;
    int wx  = wr - wy * NWIN;

    int py = wy*8 + (lane >> 3) - 4;
    int px = wx*8 + (lane & 7)  - 4;
    int iy = refl(py, IMG), ix = refl(px, IMG);
    int pxoff = b*NPX + iy*256 + ix;
    int vpx = (py >= 0 && py < IMG && px >= 0 && px < IMG) ? pxoff : (int)(pxoff | 0x80000000u);

    int pxA[4];
    #pragma unroll
    for (int mt = 0; mt < 4; ++mt)
        pxA[mt] = __builtin_amdgcn_ds_bpermute((16*mt + lc)*4, vpx) & 0x7fffffff;

    #pragma unroll 1
    for (int h = 0; h < 3; ++h) {
        // V rows -> Vt LDS (transposed): Vt[c][key=lane]
        {
            const u16* vrow = qkv + (size_t)pxoff*288 + 192 + h*32;
            #pragma unroll
            for (int g = 0; g < 4; ++g) {
                bf16x8 vv = *(const bf16x8*)(vrow + g*8);
                #pragma unroll
                for (int j = 0; j < 8; ++j)
                    Vlds[(g*8 + j)*72 + lane] = (u16)vv[j];
            }
        }

        // K A-frags (shared across q-blocks)
        bf16x8 afr[4];
        #pragma unroll
        for (int mt = 0; mt < 4; ++mt)
            afr[mt] = *(const bf16x8*)(qkv + (size_t)pxA[mt]*288 + 96 + h*32 + kg*8);

        // --- QK^T for ALL 4 q-blocks upfront ---
        f32x4 acc[4][4];                 // [nt][mt]
        #pragma unroll
        for (int nt = 0; nt < 4; ++nt) {
            const float* bb = biasS + h*4096 + (size_t)nt*1024 + lc*64 + 4*kg;
            #pragma unroll
            for (int mt = 0; mt < 4; ++mt)
                acc[nt][mt] = *(const f32x4*)(bb + mt*16);
        }
        #pragma unroll
        for (int nt = 0; nt < 4; ++nt) {
            bf16x8 qf = *(const bf16x8*)(qkv + (size_t)pxA[nt]*288 + h*32 + kg*8);
            #pragma unroll
            for (int mt = 0; mt < 4; ++mt)
                acc[nt][mt] = __builtin_amdgcn_mfma_f32_16x16x32_bf16(afr[mt], qf, acc[nt][mt], 0, 0, 0);
        }

        // --- per q-block: softmax -> P -> PV -> store (independent chains) ---
        #pragma unroll
        for (int nt = 0; nt < 4; ++nt) {
            float m = acc[nt][0][0];
            #pragma unroll
            for (int mt = 0; mt < 4; ++mt)
                #pragma unroll
                for (int r = 0; r < 4; ++r)
                    m = fmaxf(m, acc[nt][mt][r]);
            m = fmaxf(m, __shfl_xor(m, 16));
            m = fmaxf(m, __shfl_xor(m, 32));
            float mc = -m * SM_C;
            float s = 0.f;
            #pragma unroll
            for (int mt = 0; mt < 4; ++mt)
                #pragma unroll
                for (int r = 0; r < 4; ++r) {
                    float p = exp2f(fmaf(acc[nt][mt][r], SM_C, mc));
                    acc[nt][mt][r] = p;
                    s += p;
                }
            s += __shfl_xor(s, 16);
            s += __shfl_xor(s, 32);
            float inv = 1.0f / s;
            #pragma unroll
            for (int mt = 0; mt < 4; ++mt)
                #pragma unroll
                for (int r = 0; r < 4; ++r)
                    acc[nt][mt][r] *= inv;

            // P -> LDS: row = lc (q within block), key = 16mt+4kg+(0..3)
            #pragma unroll
            for (int mt = 0; mt < 4; ++mt) {
                uint2 pk;
                pk.x = pk2bf(acc[nt][mt][0], acc[nt][mt][1]);
                pk.y = pk2bf(acc[nt][mt][2], acc[nt][mt][3]);
                *(uint2*)(Plds + lc*72 + 16*mt + 4*kg) = pk;
            }

            // PV: D[q][c] = sum_key P[q][key] * V[key][c]
            f32x4 oacc[2] = {};
            #pragma unroll
            for (int s2 = 0; s2 < 2; ++s2) {
                bf16x8 pa = *(const bf16x8*)(Plds + lc*72 + s2*32 + kg*8);
                #pragma unroll
                for (int ntpv = 0; ntpv < 2; ++ntpv) {
                    bf16x8 vb2 = *(const bf16x8*)(Vlds + (16*ntpv + lc)*72 + s2*32 + kg*8);
                    oacc[ntpv] = __builtin_amdgcn_mfma_f32_16x16x32_bf16(pa, vb2, oacc[ntpv], 0, 0, 0);
                }
            }

            // store: out[q = 16nt+4kg+rr][c = 16ntpv+lc]
            #pragma unroll
            for (int rr = 0; rr < 4; ++rr) {
                int vp = __builtin_amdgcn_ds_bpermute((16*nt + 4*kg + rr)*4, vpx);
                if (vp >= 0) {
                    u16* op = att + (size_t)vp*96 + h*32 + lc;
                    op[0]  = f2bf(oacc[0][rr]);
                    op[16] = f2bf(oacc[1][rr]);
                }
            }
        }
    }
}

// ---------------------------------------------------------------- 3x3 conv + attn add + proj (fused, MFMA)
__global__ __launch_bounds__(256, 2) void k_convproj(
    const u16* __restrict__ qkv, const u16* __restrict__ att,
    const u16* __restrict__ Bfrag, const float* __restrict__ cb,
    const u16* __restrict__ BfragP, const float* __restrict__ pb,
    float* __restrict__ out)
{
    int tile = blockIdx.x;              // 0..2047
    int b    = tile >> 8;
    int tr   = tile & 255;              // 32 row-tiles x 8 col-tiles
    int ty0  = (tr >> 3) * 8;
    int tx0  = (tr & 7) * 32;
    int t    = threadIdx.x;

    __shared__ u16 vt[340 * HALO_PITCH];   // 70,720 B; phase-2 reuses as S-tile [256][104]

    for (int p = t; p < 340; p += 256) {
        int hr = p / 34;
        int hc = p - hr * 34;
        int gy = refl(ty0 - 1 + hr, IMG);
        int gx = refl(tx0 - 1 + hc, IMG);
        const uint4* src = (const uint4*)(qkv + ((size_t)(b*NPX + gy*256 + gx))*288 + 192);
        uint4* dst = (uint4*)(vt + p * HALO_PITCH);
        #pragma unroll
        for (int q = 0; q < 12; ++q) dst[q] = src[q];
    }
    __syncthreads();

    int wv   = __builtin_amdgcn_readfirstlane(t >> 6);
    int lane = t & 63;
    int lc   = lane & 15;
    int kg   = lane >> 4;

    int abase[4];
    #pragma unroll
    for (int mt = 0; mt < 4; ++mt) {
        int r_mt = 2*wv + (mt >> 1);
        int c_mt = (mt & 1) * 16;
        abase[mt] = (r_mt*34 + c_mt + lc) * HALO_PITCH + kg*8;
    }

    f32x4 acc[4][6] = {};

    const u16* bfr = Bfrag + lane*8;
    #pragma unroll 1
    for (int ck = 0; ck < 3; ++ck) {
        const u16* bck = bfr + ck * 27648;
        int aoff = ck * 32;
        #pragma unroll
        for (int tap = 0; tap < 9; ++tap) {
            const int dy = tap / 3, dx = tap % 3;
            bf16x8 bF[6];
            #pragma unroll
            for (int nt = 0; nt < 6; ++nt)
                bF[nt] = *(const bf16x8*)(bck + (tap*6 + nt)*512);
            #pragma unroll
            for (int mt = 0; mt < 4; ++mt) {
                bf16x8 aF = *(const bf16x8*)(vt + abase[mt] + aoff + (dy*34 + dx)*HALO_PITCH);
                #pragma unroll
                for (int nt = 0; nt < 6; ++nt)
                    acc[mt][nt] = __builtin_amdgcn_mfma_f32_16x16x32_bf16(aF, bF[nt], acc[mt][nt], 0, 0, 0);
            }
        }
    }

    float cbv[6];
    #pragma unroll
    for (int nt = 0; nt < 6; ++nt) cbv[nt] = cb[nt*16 + lc];

    // all conv reads of vt done -> safe to overwrite with the S-tile
    __syncthreads();

    #pragma unroll
    for (int mt = 0; mt < 4; ++mt) {
        int r_mt = 2*wv + (mt >> 1);
        int c_mt = (mt & 1) * 16;
        int y    = ty0 + r_mt;
        #pragma unroll
        for (int r = 0; r < 4; ++r) {
            int x  = tx0 + c_mt + kg*4 + r;
            int pl = r_mt*32 + c_mt + kg*4 + r;      // local pixel 0..255
            size_t pbase = ((size_t)(b*NPX + y*256 + x))*96 + lc;
            u16* srow = vt + pl * HALO_PITCH + lc;
            #pragma unroll
            for (int nt = 0; nt < 6; ++nt) {
                float v = acc[mt][nt][r] + cbv[nt] + bf2f(att[pbase + nt*16]);
                srow[nt*16] = f2bf(v);
            }
        }
    }
    __syncthreads();

    // phase 2: proj MFMA from S-tile (identical pattern to k_qkv's xs reads)
    f32x4 pacc[4][6] = {};
    const u16* bbase = BfragP + lane*8;
    #pragma unroll
    for (int kstep = 0; kstep < 3; ++kstep) {
        bf16x8 bF[6];
        #pragma unroll
        for (int nt = 0; nt < 6; ++nt)
            bF[nt] = *(const bf16x8*)(bbase + (size_t)(kstep*6 + nt)*512);
        #pragma unroll
        for (int mt = 0; mt < 4; ++mt) {
            bf16x8 aF = *(const bf16x8*)(vt + (wv*64 + mt*16 + lc)*HALO_PITCH + kstep*32 + kg*8);
            #pragma unroll
            for (int nt = 0; nt < 6; ++nt)
                pacc[mt][nt] = __builtin_amdgcn_mfma_f32_16x16x32_bf16(aF, bF[nt], pacc[mt][nt], 0, 0, 0);
        }
    }

    float bv[6];
    #pragma unroll
    for (int nt = 0; nt < 6; ++nt) bv[nt] = pb[nt*16 + lc];

    float* ob = out + (size_t)b*96*NPX;
    #pragma unroll
    for (int mt = 0; mt < 4; ++mt) {
        #pragma unroll
        for (int r = 0; r < 4; ++r) {
            int pl = wv*64 + mt*16 + kg*4 + r;       // local pixel 0..255
            int y  = ty0 + (pl >> 5);
            int x  = tx0 + (pl & 31);
            #pragma unroll
            for (int nt = 0; nt < 6; ++nt)
                ob[(size_t)(nt*16 + lc)*NPX + y*256 + x] = pacc[mt][nt][r] + bv[nt];
        }
    }
}

// ----------------------------------------------------------------
extern "C" void kernel_launch(void* const* d_in, const int* in_sizes, int n_in,
                              void* d_out, int out_size, void* d_ws, size_t ws_size,
                              hipStream_t stream)
{
    const float* x      = (const float*)d_in[0];
    const float* V_w    = (const float*)d_in[1];
    const float* V_b    = (const float*)d_in[2];
    const float* QK_w   = (const float*)d_in[3];
    const float* QK_b   = (const float*)d_in[4];
    const float* conv_w = (const float*)d_in[5];
    const float* conv_b = (const float*)d_in[6];
    const float* proj_w = (const float*)d_in[7];
    const float* proj_b = (const float*)d_in[8];
    const float* m1_w   = (const float*)d_in[9];
    const float* m1_b   = (const float*)d_in[10];
    const float* m2_w   = (const float*)d_in[11];
    const float* m2_b   = (const float*)d_in[12];
    float* out = (float*)d_out;

    char* ws = (char*)d_ws;
    float* biasS = (float*)ws;                                      // 49152 B
    u16* qkvb = (u16*)(ws + 49152);                                 // 301989888 B
    u16* attb = (u16*)(ws + 49152 + 301989888);                     // 100663296 B
    char* scr = ws + 49152 + 301989888 + 100663296;                 // free region

    u16* Bfrag  = (u16*)scr;                   // 165,888 B
    u16* BfragQ = (u16*)(scr + (1 << 20));     //  55,296 B
    u16* BfragP = (u16*)(scr + (2 << 20));     //  18,432 B

    hipLaunchKernelGGL(k_wprep,      dim3(162),     dim3(64),  0, stream, conv_w, Bfrag);
    hipLaunchKernelGGL(k_wprep_qkv,  dim3(54),      dim3(64),  0, stream, QK_w, V_w, BfragQ);
    hipLaunchKernelGGL(k_wprep_proj, dim3(18),      dim3(64),  0, stream, proj_w, BfragP);
    hipLaunchKernelGGL(k_bias,       dim3(48),      dim3(256), 0, stream, m1_w, m1_b, m2_w, m2_b, biasS);
    hipLaunchKernelGGL(k_qkv,        dim3(2048),    dim3(256), 0, stream, x, BfragQ, QK_b, V_b, qkvb);
    hipLaunchKernelGGL(k_attn,       dim3(2178),    dim3(256), 0, stream, qkvb, biasS, attb);
    hipLaunchKernelGGL(k_convproj,   dim3(2048),    dim3(256), 0, stream, qkvb, attb, Bfrag, conv_b, BfragP, proj_b, out);
}

// Round 12
// 528.819 us; speedup vs baseline: 1.0016x; 1.0016x over previous
//
#include <hip/hip_runtime.h>
#include <cstdint>

using u16 = unsigned short;
using u32 = unsigned int;
using f32x4  = __attribute__((ext_vector_type(4))) float;
using bf16x8 = __attribute__((ext_vector_type(8))) short;

#define NHEADS 3
#define WSZ 8
#define IMG 256
#define NPX 65536          // pixels per image
#define NWIN 33            // windows per side
#define ATT_SCALE 0.17677669529663687f
#define INV_SCALE 5.656854249492381f
#define SM_C 0.25505102572168217f    // ATT_SCALE * log2(e)
#define HALO_PITCH 104     // u16 per halo pixel (208 B: 96 ch + 8 pad -> conflict-free)

__device__ __forceinline__ int refl(int i, int n) {
    return i < 0 ? -i : (i >= n ? 2*n - 2 - i : i);
}
__device__ __forceinline__ float bflo(u32 u){ union{u32 i; float f;} x; x.i = u << 16; return x.f; }
__device__ __forceinline__ float bfhi(u32 u){ union{u32 i; float f;} x; x.i = u & 0xffff0000u; return x.f; }
__device__ __forceinline__ float bf2f(u16 v){ union{u32 i; float f;} x; x.i = ((u32)v) << 16; return x.f; }
__device__ __forceinline__ u16 f2bf(float f){
    union{float f; u32 i;} x; x.f = f;
    u32 r = x.i + 0x7fffu + ((x.i >> 16) & 1u);
    return (u16)(r >> 16);
}
__device__ __forceinline__ u32 pk2bf(float a, float b){
    return (u32)f2bf(a) | ((u32)f2bf(b) << 16);
}

// ---------------------------------------------------------------- bias table
// biasS[h][q][key] = bias[h][q][key] / ATT_SCALE   (scale folded into exp arg)
__global__ __launch_bounds__(256) void k_bias(
    const float* __restrict__ m1w, const float* __restrict__ m1b,
    const float* __restrict__ m2w, const float* __restrict__ m2b,
    float* __restrict__ biasS)
{
    int idx = blockIdx.x * 256 + threadIdx.x;   // 0..12287
    int hh  = idx >> 12;
    int rem = idx & 4095;
    int n = rem >> 6, m = rem & 63;             // n = query, m = key
    int di = (n >> 3) - (m >> 3);
    int dj = (n & 7)  - (m & 7);
    float fdi = copysignf(log1pf(fabsf((float)di)), (float)di);
    float fdj = copysignf(log1pf(fabsf((float)dj)), (float)dj);
    float acc = m2b[hh];
    for (int k = 0; k < 256; ++k) {
        float tv = fdi * m1w[2*k] + fdj * m1w[2*k+1] + m1b[k];
        float g  = 0.5f * tv * (1.0f + erff(tv * 0.70710678118654752f));
        acc = fmaf(g, m2w[hh*256 + k], acc);
    }
    biasS[hh*4096 + n*64 + m] = acc * INV_SCALE;
}

// ---------------------------------------------------------------- conv weight pre-pack
__global__ __launch_bounds__(64) void k_wprep(
    const float* __restrict__ cw, u16* __restrict__ Bfrag)
{
    int ks   = blockIdx.x;        // 0..161 = (ck*9+tap)*6+nt
    int lane = threadIdx.x;
    int nt    = ks % 6;
    int kstep = ks / 6;
    int tap   = kstep % 9;
    int ck    = kstep / 9;
    int dy = tap / 3, dx = tap % 3;
    int cout = nt*16 + (lane & 15);
    int cin0 = ck*32 + (lane >> 4)*8;
    u16* dst = Bfrag + (size_t)ks*512 + lane*8;
    #pragma unroll
    for (int j = 0; j < 8; ++j)
        dst[j] = f2bf(cw[((size_t)(cout*96 + cin0 + j))*9 + dy*3 + dx]);
}

// ---------------------------------------------------------------- QKV weight pre-pack
__global__ __launch_bounds__(64) void k_wprep_qkv(
    const float* __restrict__ qkw, const float* __restrict__ vw,
    u16* __restrict__ BfragQ)
{
    int ks   = blockIdx.x;        // 0..53 = kstep*18 + nt
    int lane = threadIdx.x;
    int nt    = ks % 18;
    int kstep = ks / 18;
    int o     = nt*16 + (lane & 15);
    int cin0  = kstep*32 + (lane >> 4)*8;
    const float* src = (o < 192) ? (qkw + (size_t)o*96 + cin0)
                                 : (vw + (size_t)(o - 192)*96 + cin0);
    u16* dst = BfragQ + (size_t)ks*512 + lane*8;
    #pragma unroll
    for (int j = 0; j < 8; ++j) dst[j] = f2bf(src[j]);
}

// ---------------------------------------------------------------- proj weight pre-pack
__global__ __launch_bounds__(64) void k_wprep_proj(
    const float* __restrict__ pw, u16* __restrict__ BfragP)
{
    int ks   = blockIdx.x;        // 0..17 = kstep*6 + nt
    int lane = threadIdx.x;
    int nt    = ks % 6;
    int kstep = ks / 6;
    int o     = nt*16 + (lane & 15);
    int cin0  = kstep*32 + (lane >> 4)*8;
    u16* dst = BfragP + (size_t)ks*512 + lane*8;
    #pragma unroll
    for (int j = 0; j < 8; ++j) dst[j] = f2bf(pw[(size_t)o*96 + cin0 + j]);
}

// ---------------------------------------------------------------- QKV 1x1 conv (MFMA, fused x-transpose)
__global__ __launch_bounds__(256, 2) void k_qkv(
    const float* __restrict__ x, const u16* __restrict__ BfragQ,
    const float* __restrict__ qkb, const float* __restrict__ vb,
    u16* __restrict__ qkv)
{
    int tile = blockIdx.x;                 // 0..2047
    int b    = tile >> 8;
    int pix0 = (tile & 255) * 256;
    size_t px0 = (size_t)tile * 256;       // = b*NPX + pix0
    int t    = threadIdx.x;

    __shared__ u16 xs[256 * HALO_PITCH];   // 53,248 B

    {
        const float* xb = x + (size_t)b*96*NPX + pix0 + t;
        u16* xrow = xs + t * HALO_PITCH;
        float v[96];
        #pragma unroll
        for (int c = 0; c < 96; ++c) v[c] = xb[(size_t)c * NPX];
        #pragma unroll
        for (int oct = 0; oct < 12; ++oct) {
            uint4 o;
            o.x = pk2bf(v[oct*8+0], v[oct*8+1]);
            o.y = pk2bf(v[oct*8+2], v[oct*8+3]);
            o.z = pk2bf(v[oct*8+4], v[oct*8+5]);
            o.w = pk2bf(v[oct*8+6], v[oct*8+7]);
            *(uint4*)(xrow + oct*8) = o;
        }
    }
    __syncthreads();

    int wv   = __builtin_amdgcn_readfirstlane(t >> 6);
    int lane = t & 63;
    int lc   = lane & 15;
    int kg   = lane >> 4;

    const u16* bbase = BfragQ + lane*8;

    #pragma unroll 1
    for (int og = 0; og < 3; ++og) {
        f32x4 acc[4][6] = {};
        #pragma unroll
        for (int kstep = 0; kstep < 3; ++kstep) {
            bf16x8 bF[6];
            #pragma unroll
            for (int nt = 0; nt < 6; ++nt)
                bF[nt] = *(const bf16x8*)(bbase + (size_t)(kstep*18 + og*6 + nt)*512);
            #pragma unroll
            for (int mt = 0; mt < 4; ++mt) {
                bf16x8 aF = *(const bf16x8*)(xs + (wv*64 + mt*16 + lc)*HALO_PITCH + kstep*32 + kg*8);
                #pragma unroll
                for (int nt = 0; nt < 6; ++nt)
                    acc[mt][nt] = __builtin_amdgcn_mfma_f32_16x16x32_bf16(aF, bF[nt], acc[mt][nt], 0, 0, 0);
            }
        }

        float bv[6];
        #pragma unroll
        for (int nt = 0; nt < 6; ++nt) {
            int o = og*96 + nt*16 + lc;
            bv[nt] = (o < 192) ? qkb[o] : vb[o - 192];
        }

        #pragma unroll
        for (int mt = 0; mt < 4; ++mt) {
            #pragma unroll
            for (int r = 0; r < 4; ++r) {
                size_t px = px0 + wv*64 + mt*16 + kg*4 + r;
                u16* qp = qkv + px*288 + og*96 + lc;
                #pragma unroll
                for (int nt = 0; nt < 6; ++nt)
                    qp[nt*16] = f2bf(acc[mt][nt][r] + bv[nt]);
            }
        }
    }
}

// ---------------------------------------------------------------- window attention (MFMA 16x16, hoisted-QK pipeline)
// 1 wave per window, 4 waves/block. Swapped QK^T: D[key][q] = mfma(K, Q, bias/scale).
// Per head: ALL 4 q-blocks' QK^T computed upfront (acc[4][4]), then a per-block
// stream softmax -> P[16][72] LDS (reused, same-wave DS order makes WAR safe)
// -> PV -> store. The 4 softmax chains are independent -> cross-block ILP hides
// the serial max/exp/LDS-roundtrip latency that bounded R9.
// LDS unchanged: 27,648 B/block.
__global__ __launch_bounds__(256, 4) void k_attn(
    const u16* __restrict__ qkv, const float* __restrict__ biasS,
    u16* __restrict__ att)
{
    __shared__ u16 lds[4 * 3456];        // 4 waves x (P[16][72] + Vt[32][72])
    int t    = threadIdx.x;
    int wv   = __builtin_amdgcn_readfirstlane(t >> 6);
    int lane = t & 63;
    int lc   = lane & 15;
    int kg   = lane >> 4;

    u16* Plds = lds + wv * 3456;         // [16][72] bf16
    u16* Vlds = Plds + 1152;             // [32][72] bf16

    int win = blockIdx.x * 4 + wv;       // 0..8711
    int b   = win / 1089;
    int wr  = win - b * 1089;
    int wy  = wr / NWIN;
    int wx  = wr - wy * NWIN;

    int py = wy*8 + (lane >> 3) - 4;
    int px = wx*8 + (lane & 7)  - 4;
    int iy = refl(py, IMG), ix = refl(px, IMG);
    int pxoff = b*NPX + iy*256 + ix;
    int vpx = (py >= 0 && py < IMG && px >= 0 && px < IMG) ? pxoff : (int)(pxoff | 0x80000000u);

    int pxA[4];
    #pragma unroll
    for (int mt = 0; mt < 4; ++mt)
        pxA[mt] = __builtin_amdgcn_ds_bpermute((16*mt + lc)*4, vpx) & 0x7fffffff;

    #pragma unroll 1
    for (int h = 0; h < 3; ++h) {
        // V rows -> Vt LDS (transposed): Vt[c][key=lane]
        {
            const u16* vrow = qkv + (size_t)pxoff*288 + 192 + h*32;
            #pragma unroll
            for (int g = 0; g < 4; ++g) {
                bf16x8 vv = *(const bf16x8*)(vrow + g*8);
                #pragma unroll
                for (int j = 0; j < 8; ++j)
                    Vlds[(g*8 + j)*72 + lane] = (u16)vv[j];
            }
        }

        // K A-frags (shared across q-blocks)
        bf16x8 afr[4];
        #pragma unroll
        for (int mt = 0; mt < 4; ++mt)
            afr[mt] = *(const bf16x8*)(qkv + (size_t)pxA[mt]*288 + 96 + h*32 + kg*8);

        // --- QK^T for ALL 4 q-blocks upfront ---
        f32x4 acc[4][4];                 // [nt][mt]
        #pragma unroll
        for (int nt = 0; nt < 4; ++nt) {
            const float* bb = biasS + h*4096 + (size_t)nt*1024 + lc*64 + 4*kg;
            #pragma unroll
            for (int mt = 0; mt < 4; ++mt)
                acc[nt][mt] = *(const f32x4*)(bb + mt*16);
        }
        #pragma unroll
        for (int nt = 0; nt < 4; ++nt) {
            bf16x8 qf = *(const bf16x8*)(qkv + (size_t)pxA[nt]*288 + h*32 + kg*8);
            #pragma unroll
            for (int mt = 0; mt < 4; ++mt)
                acc[nt][mt] = __builtin_amdgcn_mfma_f32_16x16x32_bf16(afr[mt], qf, acc[nt][mt], 0, 0, 0);
        }

        // --- per q-block: softmax -> P -> PV -> store (independent chains) ---
        #pragma unroll
        for (int nt = 0; nt < 4; ++nt) {
            float m = acc[nt][0][0];
            #pragma unroll
            for (int mt = 0; mt < 4; ++mt)
                #pragma unroll
                for (int r = 0; r < 4; ++r)
                    m = fmaxf(m, acc[nt][mt][r]);
            m = fmaxf(m, __shfl_xor(m, 16));
            m = fmaxf(m, __shfl_xor(m, 32));
            float mc = -m * SM_C;
            float s = 0.f;
            #pragma unroll
            for (int mt = 0; mt < 4; ++mt)
                #pragma unroll
                for (int r = 0; r < 4; ++r) {
                    float p = exp2f(fmaf(acc[nt][mt][r], SM_C, mc));
                    acc[nt][mt][r] = p;
                    s += p;
                }
            s += __shfl_xor(s, 16);
            s += __shfl_xor(s, 32);
            float inv = 1.0f / s;
            #pragma unroll
            for (int mt = 0; mt < 4; ++mt)
                #pragma unroll
                for (int r = 0; r < 4; ++r)
                    acc[nt][mt][r] *= inv;

            // P -> LDS: row = lc (q within block), key = 16mt+4kg+(0..3)
            #pragma unroll
            for (int mt = 0; mt < 4; ++mt) {
                uint2 pk;
                pk.x = pk2bf(acc[nt][mt][0], acc[nt][mt][1]);
                pk.y = pk2bf(acc[nt][mt][2], acc[nt][mt][3]);
                *(uint2*)(Plds + lc*72 + 16*mt + 4*kg) = pk;
            }

            // PV: D[q][c] = sum_key P[q][key] * V[key][c]
            f32x4 oacc[2] = {};
            #pragma unroll
            for (int s2 = 0; s2 < 2; ++s2) {
                bf16x8 pa = *(const bf16x8*)(Plds + lc*72 + s2*32 + kg*8);
                #pragma unroll
                for (int ntpv = 0; ntpv < 2; ++ntpv) {
                    bf16x8 vb2 = *(const bf16x8*)(Vlds + (16*ntpv + lc)*72 + s2*32 + kg*8);
                    oacc[ntpv] = __builtin_amdgcn_mfma_f32_16x16x32_bf16(pa, vb2, oacc[ntpv], 0, 0, 0);
                }
            }

            // store: out[q = 16nt+4kg+rr][c = 16ntpv+lc]
            #pragma unroll
            for (int rr = 0; rr < 4; ++rr) {
                int vp = __builtin_amdgcn_ds_bpermute((16*nt + 4*kg + rr)*4, vpx);
                if (vp >= 0) {
                    u16* op = att + (size_t)vp*96 + h*32 + lc;
                    op[0]  = f2bf(oacc[0][rr]);
                    op[16] = f2bf(oacc[1][rr]);
                }
            }
        }
    }
}

// ---------------------------------------------------------------- 3x3 conv + attn add + proj (fused, MFMA)
__global__ __launch_bounds__(256, 2) void k_convproj(
    const u16* __restrict__ qkv, const u16* __restrict__ att,
    const u16* __restrict__ Bfrag, const float* __restrict__ cb,
    const u16* __restrict__ BfragP, const float* __restrict__ pb,
    float* __restrict__ out)
{
    int tile = blockIdx.x;              // 0..2047
    int b    = tile >> 8;
    int tr   = tile & 255;              // 32 row-tiles x 8 col-tiles
    int ty0  = (tr >> 3) * 8;
    int tx0  = (tr & 7) * 32;
    int t    = threadIdx.x;

    __shared__ u16 vt[340 * HALO_PITCH];   // 70,720 B; phase-2 reuses as S-tile [256][104]

    for (int p = t; p < 340; p += 256) {
        int hr = p / 34;
        int hc = p - hr * 34;
        int gy = refl(ty0 - 1 + hr, IMG);
        int gx = refl(tx0 - 1 + hc, IMG);
        const uint4* src = (const uint4*)(qkv + ((size_t)(b*NPX + gy*256 + gx))*288 + 192);
        uint4* dst = (uint4*)(vt + p * HALO_PITCH);
        #pragma unroll
        for (int q = 0; q < 12; ++q) dst[q] = src[q];
    }
    __syncthreads();

    int wv   = __builtin_amdgcn_readfirstlane(t >> 6);
    int lane = t & 63;
    int lc   = lane & 15;
    int kg   = lane >> 4;

    int abase[4];
    #pragma unroll
    for (int mt = 0; mt < 4; ++mt) {
        int r_mt = 2*wv + (mt >> 1);
        int c_mt = (mt & 1) * 16;
        abase[mt] = (r_mt*34 + c_mt + lc) * HALO_PITCH + kg*8;
    }

    f32x4 acc[4][6] = {};

    const u16* bfr = Bfrag + lane*8;
    #pragma unroll 1
    for (int ck = 0; ck < 3; ++ck) {
        const u16* bck = bfr + ck * 27648;
        int aoff = ck * 32;
        #pragma unroll
        for (int tap = 0; tap < 9; ++tap) {
            const int dy = tap / 3, dx = tap % 3;
            bf16x8 bF[6];
            #pragma unroll
            for (int nt = 0; nt < 6; ++nt)
                bF[nt] = *(const bf16x8*)(bck + (tap*6 + nt)*512);
            #pragma unroll
            for (int mt = 0; mt < 4; ++mt) {
                bf16x8 aF = *(const bf16x8*)(vt + abase[mt] + aoff + (dy*34 + dx)*HALO_PITCH);
                #pragma unroll
                for (int nt = 0; nt < 6; ++nt)
                    acc[mt][nt] = __builtin_amdgcn_mfma_f32_16x16x32_bf16(aF, bF[nt], acc[mt][nt], 0, 0, 0);
            }
        }
    }

    float cbv[6];
    #pragma unroll
    for (int nt = 0; nt < 6; ++nt) cbv[nt] = cb[nt*16 + lc];

    // all conv reads of vt done -> safe to overwrite with the S-tile
    __syncthreads();

    #pragma unroll
    for (int mt = 0; mt < 4; ++mt) {
        int r_mt = 2*wv + (mt >> 1);
        int c_mt = (mt & 1) * 16;
        int y    = ty0 + r_mt;
        #pragma unroll
        for (int r = 0; r < 4; ++r) {
            int x  = tx0 + c_mt + kg*4 + r;
            int pl = r_mt*32 + c_mt + kg*4 + r;      // local pixel 0..255
            size_t pbase = ((size_t)(b*NPX + y*256 + x))*96 + lc;
            u16* srow = vt + pl * HALO_PITCH + lc;
            #pragma unroll
            for (int nt = 0; nt < 6; ++nt) {
                float v = acc[mt][nt][r] + cbv[nt] + bf2f(att[pbase + nt*16]);
                srow[nt*16] = f2bf(v);
            }
        }
    }
    __syncthreads();

    // phase 2: proj MFMA from S-tile (identical pattern to k_qkv's xs reads)
    f32x4 pacc[4][6] = {};
    const u16* bbase = BfragP + lane*8;
    #pragma unroll
    for (int kstep = 0; kstep < 3; ++kstep) {
        bf16x8 bF[6];
        #pragma unroll
        for (int nt = 0; nt < 6; ++nt)
            bF[nt] = *(const bf16x8*)(bbase + (size_t)(kstep*6 + nt)*512);
        #pragma unroll
        for (int mt = 0; mt < 4; ++mt) {
            bf16x8 aF = *(const bf16x8*)(vt + (wv*64 + mt*16 + lc)*HALO_PITCH + kstep*32 + kg*8);
            #pragma unroll
            for (int nt = 0; nt < 6; ++nt)
                pacc[mt][nt] = __builtin_amdgcn_mfma_f32_16x16x32_bf16(aF, bF[nt], pacc[mt][nt], 0, 0, 0);
        }
    }

    float bv[6];
    #pragma unroll
    for (int nt = 0; nt < 6; ++nt) bv[nt] = pb[nt*16 + lc];

    float* ob = out + (size_t)b*96*NPX;
    #pragma unroll
    for (int mt = 0; mt < 4; ++mt) {
        #pragma unroll
        for (int r = 0; r < 4; ++r) {
            int pl = wv*64 + mt*16 + kg*4 + r;       // local pixel 0..255
            int y  = ty0 + (pl >> 5);
            int x  = tx0 + (pl & 31);
            #pragma unroll
            for (int nt = 0; nt < 6; ++nt)
                ob[(size_t)(nt*16 + lc)*NPX + y*256 + x] = pacc[mt][nt][r] + bv[nt];
        }
    }
}

// ----------------------------------------------------------------
extern "C" void kernel_launch(void* const* d_in, const int* in_sizes, int n_in,
                              void* d_out, int out_size, void* d_ws, size_t ws_size,
                              hipStream_t stream)
{
    const float* x      = (const float*)d_in[0];
    const float* V_w    = (const float*)d_in[1];
    const float* V_b    = (const float*)d_in[2];
    const float* QK_w   = (const float*)d_in[3];
    const float* QK_b   = (const float*)d_in[4];
    const float* conv_w = (const float*)d_in[5];
    const float* conv_b = (const float*)d_in[6];
    const float* proj_w = (const float*)d_in[7];
    const float* proj_b = (const float*)d_in[8];
    const float* m1_w   = (const float*)d_in[9];
    const float* m1_b   = (const float*)d_in[10];
    const float* m2_w   = (const float*)d_in[11];
    const float* m2_b   = (const float*)d_in[12];
    float* out = (float*)d_out;

    char* ws = (char*)d_ws;
    float* biasS = (float*)ws;                                      // 49152 B
    u16* qkvb = (u16*)(ws + 49152);                                 // 301989888 B
    u16* attb = (u16*)(ws + 49152 + 301989888);                     // 100663296 B
    char* scr = ws + 49152 + 301989888 + 100663296;                 // free region

    u16* Bfrag  = (u16*)scr;                   // 165,888 B
    u16* BfragQ = (u16*)(scr + (1 << 20));     //  55,296 B
    u16* BfragP = (u16*)(scr + (2 << 20));     //  18,432 B

    hipLaunchKernelGGL(k_wprep,      dim3(162),     dim3(64),  0, stream, conv_w, Bfrag);
    hipLaunchKernelGGL(k_wprep_qkv,  dim3(54),      dim3(64),  0, stream, QK_w, V_w, BfragQ);
    hipLaunchKernelGGL(k_wprep_proj, dim3(18),      dim3(64),  0, stream, proj_w, BfragP);
    hipLaunchKernelGGL(k_bias,       dim3(48),      dim3(256), 0, stream, m1_w, m1_b, m2_w, m2_b, biasS);
    hipLaunchKernelGGL(k_qkv,        dim3(2048),    dim3(256), 0, stream, x, BfragQ, QK_b, V_b, qkvb);
    hipLaunchKernelGGL(k_attn,       dim3(2178),    dim3(256), 0, stream, qkvb, biasS, attb);
    hipLaunchKernelGGL(k_convproj,   dim3(2048),    dim3(256), 0, stream, qkvb, attb, Bfrag, conv_b, BfragP, proj_b, out);
}

// Round 13
// 527.601 us; speedup vs baseline: 1.0039x; 1.0023x over previous
//
#include <hip/hip_runtime.h>
#include <cstdint>

using u16 = unsigned short;
using u32 = unsigned int;
using f32x4  = __attribute__((ext_vector_type(4))) float;
using bf16x8 = __attribute__((ext_vector_type(8))) short;

#define NHEADS 3
#define WSZ 8
#define IMG 256
#define NPX 65536          // pixels per image
#define NWIN 33            // windows per side
#define ATT_SCALE 0.17677669529663687f
#define INV_SCALE 5.656854249492381f
#define SM_C 0.25505102572168217f    // ATT_SCALE * log2(e)
#define HALO_PITCH 104     // u16 per halo pixel (208 B: 96 ch + 8 pad -> conflict-free)

__device__ __forceinline__ int refl(int i, int n) {
    return i < 0 ? -i : (i >= n ? 2*n - 2 - i : i);
}
__device__ __forceinline__ float bflo(u32 u){ union{u32 i; float f;} x; x.i = u << 16; return x.f; }
__device__ __forceinline__ float bfhi(u32 u){ union{u32 i; float f;} x; x.i = u & 0xffff0000u; return x.f; }
__device__ __forceinline__ float bf2f(u16 v){ union{u32 i; float f;} x; x.i = ((u32)v) << 16; return x.f; }
__device__ __forceinline__ u16 f2bf(float f){
    union{float f; u32 i;} x; x.f = f;
    u32 r = x.i + 0x7fffu + ((x.i >> 16) & 1u);
    return (u16)(r >> 16);
}
__device__ __forceinline__ u32 pk2bf(float a, float b){
    return (u32)f2bf(a) | ((u32)f2bf(b) << 16);
}

// ---------------------------------------------------------------- bias table
// biasS[h][q][key] = bias[h][q][key] / ATT_SCALE   (scale folded into exp arg)
__global__ __launch_bounds__(256) void k_bias(
    const float* __restrict__ m1w, const float* __restrict__ m1b,
    const float* __restrict__ m2w, const float* __restrict__ m2b,
    float* __restrict__ biasS)
{
    int idx = blockIdx.x * 256 + threadIdx.x;   // 0..12287
    int hh  = idx >> 12;
    int rem = idx & 4095;
    int n = rem >> 6, m = rem & 63;             // n = query, m = key
    int di = (n >> 3) - (m >> 3);
    int dj = (n & 7)  - (m & 7);
    float fdi = copysignf(log1pf(fabsf((float)di)), (float)di);
    float fdj = copysignf(log1pf(fabsf((float)dj)), (float)dj);
    float acc = m2b[hh];
    for (int k = 0; k < 256; ++k) {
        float tv = fdi * m1w[2*k] + fdj * m1w[2*k+1] + m1b[k];
        float g  = 0.5f * tv * (1.0f + erff(tv * 0.70710678118654752f));
        acc = fmaf(g, m2w[hh*256 + k], acc);
    }
    biasS[hh*4096 + n*64 + m] = acc * INV_SCALE;
}

// ---------------------------------------------------------------- conv weight pre-pack
__global__ __launch_bounds__(64) void k_wprep(
    const float* __restrict__ cw, u16* __restrict__ Bfrag)
{
    int ks   = blockIdx.x;        // 0..161 = (ck*9+tap)*6+nt
    int lane = threadIdx.x;
    int nt    = ks % 6;
    int kstep = ks / 6;
    int tap   = kstep % 9;
    int ck    = kstep / 9;
    int dy = tap / 3, dx = tap % 3;
    int cout = nt*16 + (lane & 15);
    int cin0 = ck*32 + (lane >> 4)*8;
    u16* dst = Bfrag + (size_t)ks*512 + lane*8;
    #pragma unroll
    for (int j = 0; j < 8; ++j)
        dst[j] = f2bf(cw[((size_t)(cout*96 + cin0 + j))*9 + dy*3 + dx]);
}

// ---------------------------------------------------------------- QKV weight pre-pack
__global__ __launch_bounds__(64) void k_wprep_qkv(
    const float* __restrict__ qkw, const float* __restrict__ vw,
    u16* __restrict__ BfragQ)
{
    int ks   = blockIdx.x;        // 0..53 = kstep*18 + nt
    int lane = threadIdx.x;
    int nt    = ks % 18;
    int kstep = ks / 18;
    int o     = nt*16 + (lane & 15);
    int cin0  = kstep*32 + (lane >> 4)*8;
    const float* src = (o < 192) ? (qkw + (size_t)o*96 + cin0)
                                 : (vw + (size_t)(o - 192)*96 + cin0);
    u16* dst = BfragQ + (size_t)ks*512 + lane*8;
    #pragma unroll
    for (int j = 0; j < 8; ++j) dst[j] = f2bf(src[j]);
}

// ---------------------------------------------------------------- proj weight pre-pack
__global__ __launch_bounds__(64) void k_wprep_proj(
    const float* __restrict__ pw, u16* __restrict__ BfragP)
{
    int ks   = blockIdx.x;        // 0..17 = kstep*6 + nt
    int lane = threadIdx.x;
    int nt    = ks % 6;
    int kstep = ks / 6;
    int o     = nt*16 + (lane & 15);
    int cin0  = kstep*32 + (lane >> 4)*8;
    u16* dst = BfragP + (size_t)ks*512 + lane*8;
    #pragma unroll
    for (int j = 0; j < 8; ++j) dst[j] = f2bf(pw[(size_t)o*96 + cin0 + j]);
}

// ---------------------------------------------------------------- QKV 1x1 conv (MFMA, fused x-transpose)
__global__ __launch_bounds__(256, 2) void k_qkv(
    const float* __restrict__ x, const u16* __restrict__ BfragQ,
    const float* __restrict__ qkb, const float* __restrict__ vb,
    u16* __restrict__ qkv)
{
    int tile = blockIdx.x;                 // 0..2047
    int b    = tile >> 8;
    int pix0 = (tile & 255) * 256;
    size_t px0 = (size_t)tile * 256;       // = b*NPX + pix0
    int t    = threadIdx.x;

    __shared__ u16 xs[256 * HALO_PITCH];   // 53,248 B

    {
        const float* xb = x + (size_t)b*96*NPX + pix0 + t;
        u16* xrow = xs + t * HALO_PITCH;
        float v[96];
        #pragma unroll
        for (int c = 0; c < 96; ++c) v[c] = xb[(size_t)c * NPX];
        #pragma unroll
        for (int oct = 0; oct < 12; ++oct) {
            uint4 o;
            o.x = pk2bf(v[oct*8+0], v[oct*8+1]);
            o.y = pk2bf(v[oct*8+2], v[oct*8+3]);
            o.z = pk2bf(v[oct*8+4], v[oct*8+5]);
            o.w = pk2bf(v[oct*8+6], v[oct*8+7]);
            *(uint4*)(xrow + oct*8) = o;
        }
    }
    __syncthreads();

    int wv   = __builtin_amdgcn_readfirstlane(t >> 6);
    int lane = t & 63;
    int lc   = lane & 15;
    int kg   = lane >> 4;

    const u16* bbase = BfragQ + lane*8;

    #pragma unroll 1
    for (int og = 0; og < 3; ++og) {
        f32x4 acc[4][6] = {};
        #pragma unroll
        for (int kstep = 0; kstep < 3; ++kstep) {
            bf16x8 bF[6];
            #pragma unroll
            for (int nt = 0; nt < 6; ++nt)
                bF[nt] = *(const bf16x8*)(bbase + (size_t)(kstep*18 + og*6 + nt)*512);
            #pragma unroll
            for (int mt = 0; mt < 4; ++mt) {
                bf16x8 aF = *(const bf16x8*)(xs + (wv*64 + mt*16 + lc)*HALO_PITCH + kstep*32 + kg*8);
                #pragma unroll
                for (int nt = 0; nt < 6; ++nt)
                    acc[mt][nt] = __builtin_amdgcn_mfma_f32_16x16x32_bf16(aF, bF[nt], acc[mt][nt], 0, 0, 0);
            }
        }

        float bv[6];
        #pragma unroll
        for (int nt = 0; nt < 6; ++nt) {
            int o = og*96 + nt*16 + lc;
            bv[nt] = (o < 192) ? qkb[o] : vb[o - 192];
        }

        #pragma unroll
        for (int mt = 0; mt < 4; ++mt) {
            #pragma unroll
            for (int r = 0; r < 4; ++r) {
                size_t px = px0 + wv*64 + mt*16 + kg*4 + r;
                u16* qp = qkv + px*288 + og*96 + lc;
                #pragma unroll
                for (int nt = 0; nt < 6; ++nt)
                    qp[nt*16] = f2bf(acc[mt][nt][r] + bv[nt]);
            }
        }
    }
}

// ---------------------------------------------------------------- window attention (MFMA 16x16, hoisted-QK pipeline)
// 1 wave per window, 4 waves/block. Swapped QK^T: D[key][q] = mfma(K, Q, bias/scale).
// Per head: ALL 4 q-blocks' QK^T computed upfront (acc[4][4]), then a per-block
// stream softmax -> P[16][72] LDS (reused, same-wave DS order makes WAR safe)
// -> PV -> store. The 4 softmax chains are independent -> cross-block ILP hides
// the serial max/exp/LDS-roundtrip latency that bounded R9.
// LDS unchanged: 27,648 B/block.
__global__ __launch_bounds__(256, 4) void k_attn(
    const u16* __restrict__ qkv, const float* __restrict__ biasS,
    u16* __restrict__ att)
{
    __shared__ u16 lds[4 * 3456];        // 4 waves x (P[16][72] + Vt[32][72])
    int t    = threadIdx.x;
    int wv   = __builtin_amdgcn_readfirstlane(t >> 6);
    int lane = t & 63;
    int lc   = lane & 15;
    int kg   = lane >> 4;

    u16* Plds = lds + wv * 3456;         // [16][72] bf16
    u16* Vlds = Plds + 1152;             // [32][72] bf16

    int win = blockIdx.x * 4 + wv;       // 0..8711
    int b   = win / 1089;
    int wr  = win - b * 1089;
    int wy  = wr / NWIN;
    int wx  = wr - wy * NWIN;

    int py = wy*8 + (lane >> 3) - 4;
    int px = wx*8 + (lane & 7)  - 4;
    int iy = refl(py, IMG), ix = refl(px, IMG);
    int pxoff = b*NPX + iy*256 + ix;
    int vpx = (py >= 0 && py < IMG && px >= 0 && px < IMG) ? pxoff : (int)(pxoff | 0x80000000u);

    int pxA[4];
    #pragma unroll
    for (int mt = 0; mt < 4; ++mt)
        pxA[mt] = __builtin_amdgcn_ds_bpermute((16*mt + lc)*4, vpx) & 0x7fffffff;

    #pragma unroll 1
    for (int h = 0; h < 3; ++h) {
        // V rows -> Vt LDS (transposed): Vt[c][key=lane]
        {
            const u16* vrow = qkv + (size_t)pxoff*288 + 192 + h*32;
            #pragma unroll
            for (int g = 0; g < 4; ++g) {
                bf16x8 vv = *(const bf16x8*)(vrow + g*8);
                #pragma unroll
                for (int j = 0; j < 8; ++j)
                    Vlds[(g*8 + j)*72 + lane] = (u16)vv[j];
            }
        }

        // K A-frags (shared across q-blocks)
        bf16x8 afr[4];
        #pragma unroll
        for (int mt = 0; mt < 4; ++mt)
            afr[mt] = *(const bf16x8*)(qkv + (size_t)pxA[mt]*288 + 96 + h*32 + kg*8);

        // --- QK^T for ALL 4 q-blocks upfront ---
        f32x4 acc[4][4];                 // [nt][mt]
        #pragma unroll
        for (int nt = 0; nt < 4; ++nt) {
            const float* bb = biasS + h*4096 + (size_t)nt*1024 + lc*64 + 4*kg;
            #pragma unroll
            for (int mt = 0; mt < 4; ++mt)
                acc[nt][mt] = *(const f32x4*)(bb + mt*16);
        }
        #pragma unroll
        for (int nt = 0; nt < 4; ++nt) {
            bf16x8 qf = *(const bf16x8*)(qkv + (size_t)pxA[nt]*288 + h*32 + kg*8);
            #pragma unroll
            for (int mt = 0; mt < 4; ++mt)
                acc[nt][mt] = __builtin_amdgcn_mfma_f32_16x16x32_bf16(afr[mt], qf, acc[nt][mt], 0, 0, 0);
        }

        // --- per q-block: softmax -> P -> PV -> store (independent chains) ---
        #pragma unroll
        for (int nt = 0; nt < 4; ++nt) {
            float m = acc[nt][0][0];
            #pragma unroll
            for (int mt = 0; mt < 4; ++mt)
                #pragma unroll
                for (int r = 0; r < 4; ++r)
                    m = fmaxf(m, acc[nt][mt][r]);
            m = fmaxf(m, __shfl_xor(m, 16));
            m = fmaxf(m, __shfl_xor(m, 32));
            float mc = -m * SM_C;
            float s = 0.f;
            #pragma unroll
            for (int mt = 0; mt < 4; ++mt)
                #pragma unroll
                for (int r = 0; r < 4; ++r) {
                    float p = exp2f(fmaf(acc[nt][mt][r], SM_C, mc));
                    acc[nt][mt][r] = p;
                    s += p;
                }
            s += __shfl_xor(s, 16);
            s += __shfl_xor(s, 32);
            float inv = 1.0f / s;
            #pragma unroll
            for (int mt = 0; mt < 4; ++mt)
                #pragma unroll
                for (int r = 0; r < 4; ++r)
                    acc[nt][mt][r] *= inv;

            // P -> LDS: row = lc (q within block), key = 16mt+4kg+(0..3)
            #pragma unroll
            for (int mt = 0; mt < 4; ++mt) {
                uint2 pk;
                pk.x = pk2bf(acc[nt][mt][0], acc[nt][mt][1]);
                pk.y = pk2bf(acc[nt][mt][2], acc[nt][mt][3]);
                *(uint2*)(Plds + lc*72 + 16*mt + 4*kg) = pk;
            }

            // PV: D[q][c] = sum_key P[q][key] * V[key][c]
            f32x4 oacc[2] = {};
            #pragma unroll
            for (int s2 = 0; s2 < 2; ++s2) {
                bf16x8 pa = *(const bf16x8*)(Plds + lc*72 + s2*32 + kg*8);
                #pragma unroll
                for (int ntpv = 0; ntpv < 2; ++ntpv) {
                    bf16x8 vb2 = *(const bf16x8*)(Vlds + (16*ntpv + lc)*72 + s2*32 + kg*8);
                    oacc[ntpv] = __builtin_amdgcn_mfma_f32_16x16x32_bf16(pa, vb2, oacc[ntpv], 0, 0, 0);
                }
            }

            // store: out[q = 16nt+4kg+rr][c = 16ntpv+lc]
            #pragma unroll
            for (int rr = 0; rr < 4; ++rr) {
                int vp = __builtin_amdgcn_ds_bpermute((16*nt + 4*kg + rr)*4, vpx);
                if (vp >= 0) {
                    u16* op = att + (size_t)vp*96 + h*32 + lc;
                    op[0]  = f2bf(oacc[0][rr]);
                    op[16] = f2bf(oacc[1][rr]);
                }
            }
        }
    }
}

// ---------------------------------------------------------------- 3x3 conv + attn add + proj (fused, MFMA)
__global__ __launch_bounds__(256, 2) void k_convproj(
    const u16* __restrict__ qkv, const u16* __restrict__ att,
    const u16* __restrict__ Bfrag, const float* __restrict__ cb,
    const u16* __restrict__ BfragP, const float* __restrict__ pb,
    float* __restrict__ out)
{
    int tile = blockIdx.x;              // 0..2047
    int b    = tile >> 8;
    int tr   = tile & 255;              // 32 row-tiles x 8 col-tiles
    int ty0  = (tr >> 3) * 8;
    int tx0  = (tr & 7) * 32;
    int t    = threadIdx.x;

    __shared__ u16 vt[340 * HALO_PITCH];   // 70,720 B; phase-2 reuses as S-tile [256][104]

    for (int p = t; p < 340; p += 256) {
        int hr = p / 34;
        int hc = p - hr * 34;
        int gy = refl(ty0 - 1 + hr, IMG);
        int gx = refl(tx0 - 1 + hc, IMG);
        const uint4* src = (const uint4*)(qkv + ((size_t)(b*NPX + gy*256 + gx))*288 + 192);
        uint4* dst = (uint4*)(vt + p * HALO_PITCH);
        #pragma unroll
        for (int q = 0; q < 12; ++q) dst[q] = src[q];
    }
    __syncthreads();

    int wv   = __builtin_amdgcn_readfirstlane(t >> 6);
    int lane = t & 63;
    int lc   = lane & 15;
    int kg   = lane >> 4;

    int abase[4];
    #pragma unroll
    for (int mt = 0; mt < 4; ++mt) {
        int r_mt = 2*wv + (mt >> 1);
        int c_mt = (mt & 1) * 16;
        abase[mt] = (r_mt*34 + c_mt + lc) * HALO_PITCH + kg*8;
    }

    f32x4 acc[4][6] = {};

    const u16* bfr = Bfrag + lane*8;
    #pragma unroll 1
    for (int ck = 0; ck < 3; ++ck) {
        const u16* bck = bfr + ck * 27648;
        int aoff = ck * 32;
        #pragma unroll
        for (int tap = 0; tap < 9; ++tap) {
            const int dy = tap / 3, dx = tap % 3;
            bf16x8 bF[6];
            #pragma unroll
            for (int nt = 0; nt < 6; ++nt)
                bF[nt] = *(const bf16x8*)(bck + (tap*6 + nt)*512);
            #pragma unroll
            for (int mt = 0; mt < 4; ++mt) {
                bf16x8 aF = *(const bf16x8*)(vt + abase[mt] + aoff + (dy*34 + dx)*HALO_PITCH);
                #pragma unroll
                for (int nt = 0; nt < 6; ++nt)
                    acc[mt][nt] = __builtin_amdgcn_mfma_f32_16x16x32_bf16(aF, bF[nt], acc[mt][nt], 0, 0, 0);
            }
        }
    }

    float cbv[6];
    #pragma unroll
    for (int nt = 0; nt < 6; ++nt) cbv[nt] = cb[nt*16 + lc];

    // all conv reads of vt done -> safe to overwrite with the S-tile
    __syncthreads();

    #pragma unroll
    for (int mt = 0; mt < 4; ++mt) {
        int r_mt = 2*wv + (mt >> 1);
        int c_mt = (mt & 1) * 16;
        int y    = ty0 + r_mt;
        #pragma unroll
        for (int r = 0; r < 4; ++r) {
            int x  = tx0 + c_mt + kg*4 + r;
            int pl = r_mt*32 + c_mt + kg*4 + r;      // local pixel 0..255
            size_t pbase = ((size_t)(b*NPX + y*256 + x))*96 + lc;
            u16* srow = vt + pl * HALO_PITCH + lc;
            #pragma unroll
            for (int nt = 0; nt < 6; ++nt) {
                float v = acc[mt][nt][r] + cbv[nt] + bf2f(att[pbase + nt*16]);
                srow[nt*16] = f2bf(v);
            }
        }
    }
    __syncthreads();

    // phase 2: proj MFMA from S-tile (identical pattern to k_qkv's xs reads)
    f32x4 pacc[4][6] = {};
    const u16* bbase = BfragP + lane*8;
    #pragma unroll
    for (int kstep = 0; kstep < 3; ++kstep) {
        bf16x8 bF[6];
        #pragma unroll
        for (int nt = 0; nt < 6; ++nt)
            bF[nt] = *(const bf16x8*)(bbase + (size_t)(kstep*6 + nt)*512);
        #pragma unroll
        for (int mt = 0; mt < 4; ++mt) {
            bf16x8 aF = *(const bf16x8*)(vt + (wv*64 + mt*16 + lc)*HALO_PITCH + kstep*32 + kg*8);
            #pragma unroll
            for (int nt = 0; nt < 6; ++nt)
                pacc[mt][nt] = __builtin_amdgcn_mfma_f32_16x16x32_bf16(aF, bF[nt], pacc[mt][nt], 0, 0, 0);
        }
    }

    float bv[6];
    #pragma unroll
    for (int nt = 0; nt < 6; ++nt) bv[nt] = pb[nt*16 + lc];

    float* ob = out + (size_t)b*96*NPX;
    #pragma unroll
    for (int mt = 0; mt < 4; ++mt) {
        #pragma unroll
        for (int r = 0; r < 4; ++r) {
            int pl = wv*64 + mt*16 + kg*4 + r;       // local pixel 0..255
            int y  = ty0 + (pl >> 5);
            int x  = tx0 + (pl & 31);
            #pragma unroll
            for (int nt = 0; nt < 6; ++nt)
                ob[(size_t)(nt*16 + lc)*NPX + y*256 + x] = pacc[mt][nt][r] + bv[nt];
        }
    }
}

// ----------------------------------------------------------------
extern "C" void kernel_launch(void* const* d_in, const int* in_sizes, int n_in,
                              void* d_out, int out_size, void* d_ws, size_t ws_size,
                              hipStream_t stream)
{
    const float* x      = (const float*)d_in[0];
    const float* V_w    = (const float*)d_in[1];
    const float* V_b    = (const float*)d_in[2];
    const float* QK_w   = (const float*)d_in[3];
    const float* QK_b   = (const float*)d_in[4];
    const float* conv_w = (const float*)d_in[5];
    const float* conv_b = (const float*)d_in[6];
    const float* proj_w = (const float*)d_in[7];
    const float* proj_b = (const float*)d_in[8];
    const float* m1_w   = (const float*)d_in[9];
    const float* m1_b   = (const float*)d_in[10];
    const float* m2_w   = (const float*)d_in[11];
    const float* m2_b   = (const float*)d_in[12];
    float* out = (float*)d_out;

    char* ws = (char*)d_ws;
    float* biasS = (float*)ws;                                      // 49152 B
    u16* qkvb = (u16*)(ws + 49152);                                 // 301989888 B
    u16* attb = (u16*)(ws + 49152 + 301989888);                     // 100663296 B
    char* scr = ws + 49152 + 301989888 + 100663296;                 // free region

    u16* Bfrag  = (u16*)scr;                   // 165,888 B
    u16* BfragQ = (u16*)(scr + (1 << 20));     //  55,296 B
    u16* BfragP = (u16*)(scr + (2 << 20));     //  18,432 B

    hipLaunchKernelGGL(k_wprep,      dim3(162),     dim3(64),  0, stream, conv_w, Bfrag);
    hipLaunchKernelGGL(k_wprep_qkv,  dim3(54),      dim3(64),  0, stream, QK_w, V_w, BfragQ);
    hipLaunchKernelGGL(k_wprep_proj, dim3(18),      dim3(64),  0, stream, proj_w, BfragP);
    hipLaunchKernelGGL(k_bias,       dim3(48),      dim3(256), 0, stream, m1_w, m1_b, m2_w, m2_b, biasS);
    hipLaunchKernelGGL(k_qkv,        dim3(2048),    dim3(256), 0, stream, x, BfragQ, QK_b, V_b, qkvb);
    hipLaunchKernelGGL(k_attn,       dim3(2178),    dim3(256), 0, stream, qkvb, biasS, attb);
    hipLaunchKernelGGL(k_convproj,   dim3(2048),    dim3(256), 0, stream, qkvb, attb, Bfrag, conv_b, BfragP, proj_b, out);
}